// Round 2
// baseline (1231.541 us; speedup 1.0000x reference)
//
#include <hip/hip_runtime.h>

#define IN_F 4096
#define OUT_F 11008
#define GROUPSZ 128
#define NGROUPS 32
#define M_TOTAL 8192

typedef _Float16 half_t;
typedef __attribute__((ext_vector_type(8))) _Float16 half8;
typedef __attribute__((ext_vector_type(4))) _Float16 half4v;
typedef __attribute__((ext_vector_type(4))) float f32x4;
typedef __attribute__((ext_vector_type(4))) int i32x4;

typedef __attribute__((address_space(1))) const void gvoid_t;
typedef __attribute__((address_space(3))) void lvoid_t;

// ---------------- prepass 1: x fp32 -> fp16 (RTNE, matches astype(fp16)) ----------------
__global__ void convert_x_k(const float* __restrict__ x, half_t* __restrict__ xh) {
  const int n4 = M_TOTAL * IN_F / 4;  // 8,388,608 quads
  int stride = gridDim.x * blockDim.x;
  for (int i = blockIdx.x * blockDim.x + threadIdx.x; i < n4; i += stride) {
    f32x4 v = ((const f32x4*)x)[i];
    half4v h;
    h[0] = (_Float16)v[0];
    h[1] = (_Float16)v[1];
    h[2] = (_Float16)v[2];
    h[3] = (_Float16)v[3];
    ((half4v*)xh)[i] = h;
  }
}

// ---------------- prepass 2: W (int32-materialized int8) * group scale -> fp16 ----------
// NOTE: harness materializes integer inputs as int32 — one int32 per weight.
__global__ void dequant_w_k(const int* __restrict__ wq,
                            const float* __restrict__ scales,
                            half_t* __restrict__ wh) {
  int row = blockIdx.x;        // OUT_F rows
  int t = threadIdx.x;         // 512 threads, 8 weights each (IN_F/8 = 512)
  size_t base = (size_t)row * IN_F + (size_t)t * 8;
  float s = scales[row * NGROUPS + (t >> 4)];  // t*8/128 = t>>4
  i32x4 q0 = ((const i32x4*)(wq + base))[0];
  i32x4 q1 = ((const i32x4*)(wq + base))[1];
  half8 h;
#pragma unroll
  for (int j = 0; j < 4; ++j) h[j] = (_Float16)((float)q0[j] * s);
#pragma unroll
  for (int j = 0; j < 4; ++j) h[4 + j] = (_Float16)((float)q1[j] * s);
  *(half8*)(wh + base) = h;
}

// ---------------- main GEMM: C[M,N] = A[M,K] * B[N,K]^T (both fp16, K-contiguous) --------
#define BM 128
#define BN 128
#define BK 32

__device__ __forceinline__ void stage_tile(const half_t* __restrict__ gA,
                                           const half_t* __restrict__ gB,
                                           half_t* sA, half_t* sB,
                                           int row0, int col0, int kt,
                                           int wave, int lane) {
  // Each global_load_lds: 64 lanes x 16B = 1024B = 16 rows of 64B.
  // LDS dest is wave-uniform base + lane*16; lane l -> row l>>2, k-half (l&3)*8.
#pragma unroll
  for (int i = 0; i < 2; ++i) {
    int rr = wave * 32 + i * 16;
    const half_t* g = gA + (size_t)(row0 + rr + (lane >> 2)) * IN_F + kt + (lane & 3) * 8;
    half_t* l = sA + rr * BK;  // wave-uniform
    __builtin_amdgcn_global_load_lds((gvoid_t*)g, (lvoid_t*)l, 16, 0, 0);
  }
#pragma unroll
  for (int i = 0; i < 2; ++i) {
    int rr = wave * 32 + i * 16;
    const half_t* g = gB + (size_t)(col0 + rr + (lane >> 2)) * IN_F + kt + (lane & 3) * 8;
    half_t* l = sB + rr * BK;
    __builtin_amdgcn_global_load_lds((gvoid_t*)g, (lvoid_t*)l, 16, 0, 0);
  }
}

__global__ __launch_bounds__(256) void gemm_k(const half_t* __restrict__ A,
                                              const half_t* __restrict__ B,
                                              const float* __restrict__ bias,
                                              float* __restrict__ C) {
  __shared__ __align__(16) half_t As[2][BM * BK];
  __shared__ __align__(16) half_t Bs[2][BN * BK];

  const int tid = threadIdx.x;
  const int lane = tid & 63;
  const int wave = tid >> 6;
  const int wm = wave & 1;   // 2x2 wave grid, each wave owns 64x64
  const int wn = wave >> 1;

  // XCD-aware swizzle; nwg = 5504, 5504 % 8 == 0 -> simple swizzle is bijective
  const int nwg = gridDim.x;
  const int swz = ((int)(blockIdx.x & 7)) * (nwg >> 3) + ((int)blockIdx.x >> 3);
  const int bm = swz & 63;  // M/BM = 64; fastest -> consecutive blocks share B panel
  const int bn = swz >> 6;
  const int row0 = bm * BM;
  const int col0 = bn * BN;

  f32x4 acc[4][4];
#pragma unroll
  for (int m = 0; m < 4; ++m)
#pragma unroll
    for (int n = 0; n < 4; ++n) acc[m][n] = (f32x4){0.f, 0.f, 0.f, 0.f};

  const int r16 = lane & 15;
  const int koff = (lane >> 4) * 8;  // A/B frag: row/col = lane&15, k-group (lane>>4)
                                     // (same lane->k map on A and B: any k-perm cancels)

  stage_tile(A, B, As[0], Bs[0], row0, col0, 0, wave, lane);

  int cur = 0;
  const int nk = IN_F / BK;  // 128
  for (int kt = 0; kt < nk; ++kt) {
    __syncthreads();  // vmcnt(0)+barrier: buf[cur] staged; all reads of buf[cur^1] done
    if (kt + 1 < nk)
      stage_tile(A, B, As[cur ^ 1], Bs[cur ^ 1], row0, col0, (kt + 1) * BK, wave, lane);

    half8 a[4], b[4];
#pragma unroll
    for (int m = 0; m < 4; ++m)
      a[m] = *(const half8*)&As[cur][(wm * 64 + m * 16 + r16) * BK + koff];
#pragma unroll
    for (int n = 0; n < 4; ++n)
      b[n] = *(const half8*)&Bs[cur][(wn * 64 + n * 16 + r16) * BK + koff];
#pragma unroll
    for (int m = 0; m < 4; ++m)
#pragma unroll
      for (int n = 0; n < 4; ++n)
        acc[m][n] = __builtin_amdgcn_mfma_f32_16x16x32_f16(a[m], b[n], acc[m][n], 0, 0, 0);
    cur ^= 1;
  }

  // Epilogue: fp16 rounding + fp16 bias add, matching reference numerics.
  // C/D layout: col = lane&15, row = (lane>>4)*4 + r  [m89/m91]
#pragma unroll
  for (int n = 0; n < 4; ++n) {
    int col = col0 + wn * 64 + n * 16 + r16;
    _Float16 bh = (_Float16)bias[col];
#pragma unroll
    for (int m = 0; m < 4; ++m) {
      int rbase = row0 + wm * 64 + m * 16 + (lane >> 4) * 4;
#pragma unroll
      for (int r = 0; r < 4; ++r) {
        _Float16 v = (_Float16)acc[m][n][r] + bh;
        C[(size_t)(rbase + r) * OUT_F + col] = (float)v;
      }
    }
  }
}

// ---------------- emergency fallback (ws too small): correct but slow ----------------
__global__ void naive_k(const float* __restrict__ x, const int* __restrict__ wq,
                        const float* __restrict__ scales, const float* __restrict__ bias,
                        float* __restrict__ out) {
  long idx = (long)blockIdx.x * blockDim.x + threadIdx.x;
  if (idx >= (long)M_TOTAL * OUT_F) return;
  int m = (int)(idx / OUT_F);
  int n = (int)(idx % OUT_F);
  float acc = 0.f;
  for (int g = 0; g < NGROUPS; ++g) {
    float s = scales[n * NGROUPS + g];
    for (int k = g * GROUPSZ; k < (g + 1) * GROUPSZ; ++k) {
      _Float16 xv = (_Float16)x[(size_t)m * IN_F + k];
      _Float16 wv = (_Float16)((float)wq[(size_t)n * IN_F + k] * s);
      acc += (float)xv * (float)wv;
    }
  }
  _Float16 r = (_Float16)acc + (_Float16)bias[n];
  out[idx] = (float)r;
}

extern "C" void kernel_launch(void* const* d_in, const int* in_sizes, int n_in,
                              void* d_out, int out_size, void* d_ws, size_t ws_size,
                              hipStream_t stream) {
  const float* x = (const float*)d_in[0];
  const int* wq = (const int*)d_in[1];        // integer inputs arrive as int32
  const float* scales = (const float*)d_in[2];
  const float* bias = (const float*)d_in[3];
  float* out = (float*)d_out;

  const size_t xh_bytes = (size_t)M_TOTAL * IN_F * sizeof(half_t);   // 64 MiB
  const size_t wh_bytes = (size_t)OUT_F * IN_F * sizeof(half_t);     // 86 MiB

  if (ws_size >= xh_bytes + wh_bytes) {
    half_t* xh = (half_t*)d_ws;
    half_t* wh = (half_t*)((char*)d_ws + xh_bytes);
    convert_x_k<<<2048, 256, 0, stream>>>(x, xh);
    dequant_w_k<<<OUT_F, 512, 0, stream>>>(wq, scales, wh);  // row per block, 8 wts/thread
    gemm_k<<<(M_TOTAL / BM) * (OUT_F / BN), 256, 0, stream>>>(xh, wh, bias, out);
  } else {
    long total = (long)M_TOTAL * OUT_F;
    naive_k<<<(int)((total + 255) / 256), 256, 0, stream>>>(x, wq, scales, bias, out);
  }
}

// Round 3
// 977.747 us; speedup vs baseline: 1.2596x; 1.2596x over previous
//
#include <hip/hip_runtime.h>

#define IN_F 4096
#define OUT_F 11008
#define NGROUPS 32
#define M_TOTAL 8192
#define BM 256
#define BN 256
#define BK 64
#define NKT (IN_F / BK)  // 64 K-tiles

typedef _Float16 half_t;
typedef __attribute__((ext_vector_type(8))) _Float16 half8;
typedef __attribute__((ext_vector_type(4))) _Float16 half4v;
typedef __attribute__((ext_vector_type(4))) float f32x4;
typedef __attribute__((ext_vector_type(4))) int i32x4;

typedef __attribute__((address_space(1))) const void gvoid_t;
typedef __attribute__((address_space(3))) void lvoid_t;

// ---------------- prepass 1: x fp32 -> fp16 (RTNE) ----------------
__global__ void convert_x_k(const float* __restrict__ x, half_t* __restrict__ xh) {
  const int n4 = M_TOTAL * IN_F / 4;
  int stride = gridDim.x * blockDim.x;
  for (int i = blockIdx.x * blockDim.x + threadIdx.x; i < n4; i += stride) {
    f32x4 v = ((const f32x4*)x)[i];
    half4v h;
    h[0] = (_Float16)v[0]; h[1] = (_Float16)v[1];
    h[2] = (_Float16)v[2]; h[3] = (_Float16)v[3];
    ((half4v*)xh)[i] = h;
  }
}

// ---------------- prepass 2: W (int32-materialized int8) * group scale -> fp16 ----------
__global__ void dequant_w_k(const int* __restrict__ wq,
                            const float* __restrict__ scales,
                            half_t* __restrict__ wh) {
  int row = blockIdx.x;
  int t = threadIdx.x;  // 512 threads, 8 weights each
  size_t base = (size_t)row * IN_F + (size_t)t * 8;
  float s = scales[row * NGROUPS + (t >> 4)];
  i32x4 q0 = ((const i32x4*)(wq + base))[0];
  i32x4 q1 = ((const i32x4*)(wq + base))[1];
  half8 h;
#pragma unroll
  for (int j = 0; j < 4; ++j) h[j] = (_Float16)((float)q0[j] * s);
#pragma unroll
  for (int j = 0; j < 4; ++j) h[4 + j] = (_Float16)((float)q1[j] * s);
  *(half8*)(wh + base) = h;
}

// ---------------- 256x256 8-phase GEMM: C[M,N] = A[M,K] * B[N,K]^T ----------------
// LDS: [slot][op A=0/B=1][khalf][256 rows x 32 k] fp16 (64 B rows), 128 KiB total.
// T2 swizzle: byte-col c' = c ^ ((row&6)<<3); applied to pre-swizzled global source
// (linear global_load_lds dest) AND the ds_read address (rule 21: both-sides).

__device__ __forceinline__ void rd4(half8 (&d)[4], const char* base) {
#pragma unroll
  for (int i = 0; i < 4; ++i) d[i] = *(const half8*)(base + i * 1024);
}

__device__ __forceinline__ void mfma16(f32x4 (&acc)[8][4], const half8 (&a)[4],
                                       const half8 (&b)[4], int mh) {
#pragma unroll
  for (int i = 0; i < 4; ++i)
#pragma unroll
    for (int j = 0; j < 4; ++j)
      acc[mh * 4 + i][j] =
          __builtin_amdgcn_mfma_f32_16x16x32_f16(a[i], b[j], acc[mh * 4 + i][j], 0, 0, 0);
}

#define BAR() __builtin_amdgcn_s_barrier()
#define VMCNT(N) asm volatile("s_waitcnt vmcnt(" #N ")" ::: "memory")
#define PHASE_TAIL()                                   \
  do {                                                 \
    BAR();                                             \
    asm volatile("s_waitcnt lgkmcnt(0)" ::: "memory"); \
    __builtin_amdgcn_sched_barrier(0);                 \
    __builtin_amdgcn_s_setprio(1);                     \
  } while (0)
#define PHASE_END()                \
  do {                             \
    __builtin_amdgcn_s_setprio(0); \
    BAR();                         \
  } while (0)
#define PHASE_END_V4()             \
  do {                             \
    __builtin_amdgcn_s_setprio(0); \
    VMCNT(4);                      \
    BAR();                         \
  } while (0)

// Stage one 16 KiB half-tile (op, khalf) of K-tile KT into slot S. 2 loads/thread.
// Global src carries the inverse swizzle; LDS dest is linear (wave base + lane*16).
#define STAGE(OP, KH, KT, S)                                                          \
  do {                                                                                \
    const half_t* g_ = ((OP) ? pBsrc : pAsrc) + (KT) * 64 + (KH) * 32;                \
    char* d_ = (char*)&lds[S][OP][KH][0] + wvoff;                                     \
    __builtin_amdgcn_global_load_lds((gvoid_t*)g_, (lvoid_t*)d_, 16, 0, 0);           \
    __builtin_amdgcn_global_load_lds((gvoid_t*)(g_ + 128 * IN_F),                     \
                                     (lvoid_t*)(d_ + 8192), 16, 0, 0);                \
  } while (0)

__global__ __launch_bounds__(512, 2) void gemm_k(const half_t* __restrict__ A,
                                                 const half_t* __restrict__ B,
                                                 const float* __restrict__ bias,
                                                 float* __restrict__ C) {
  __shared__ __align__(16) half_t lds[2][2][2][8192];  // 128 KiB

  const int tid = threadIdx.x;
  const int lane = tid & 63;
  const int wv = tid >> 6;   // 8 waves
  const int wm = wv >> 2;    // 2 wave-rows  (128 rows each)
  const int wn = wv & 3;     // 4 wave-cols  (64 cols each)
  const int wvoff = wv << 10;  // wave-uniform LDS base step (64 lanes * 16 B)

  // XCD-bijective swizzle (nwg = 32*43 = 1376, %8 == 0); bm fastest -> B panel L2-resident
  const int nwg = gridDim.x;
  const int swz = ((int)(blockIdx.x & 7)) * (nwg >> 3) + ((int)blockIdx.x >> 3);
  const int bm = swz & 31;   // M/BM = 32
  const int bn = swz >> 5;   // N/BN = 43
  const int row0 = bm * BM;
  const int col0 = bn * BN;

  // staging source (pre-swizzled): thread -> linear dest byte L = tid*16 (+round*8192)
  const int c16 = (tid & 3) * 16;                 // dest byte col in 64 B row
  const int srow = tid >> 2;                      // dest row 0..127 (round 0)
  const int clog = c16 ^ ((srow & 6) << 3);       // logical byte col (involution)
  const int kidx = clog >> 1;                     // element 0..31 within k-half
  const half_t* pAsrc = A + (size_t)(row0 + srow) * IN_F + kidx;
  const half_t* pBsrc = B + (size_t)(col0 + srow) * IN_F + kidx;

  // fragment read offsets (swizzled); frag stride = 16 rows * 64 B = 1024
  const int r16 = lane & 15;
  const int kg = lane >> 4;                       // k-group 0..3 -> byte col kg*16
  const int arow = wm * 128 + r16;
  const int brow = wn * 64 + r16;
  const int aoff = arow * 64 + ((kg * 16) ^ ((arow & 6) << 3));
  const int boff = brow * 64 + ((kg * 16) ^ ((brow & 6) << 3));

  f32x4 acc[8][4];
#pragma unroll
  for (int m = 0; m < 8; ++m)
#pragma unroll
    for (int n = 0; n < 4; ++n) acc[m][n] = (f32x4){0.f, 0.f, 0.f, 0.f};

  // prologue: stage K-tile 0 (A-kh0, B-kh0, A-kh1, B-kh1) into slot 0
  STAGE(0, 0, 0, 0);
  STAGE(1, 0, 0, 0);
  STAGE(0, 1, 0, 0);
  STAGE(1, 1, 0, 0);
  VMCNT(4);  // kh0 pair landed; kh1 pair may stay in flight
  BAR();

  half8 a[4], b[4];
  for (int t = 0; t < NKT - 1; ++t) {
    const int s = t & 1, ns = s ^ 1;
    const char* Ab0 = (const char*)&lds[s][0][0][0];
    const char* Bb0 = (const char*)&lds[s][1][0][0];
    const char* Ab1 = (const char*)&lds[s][0][1][0];
    const char* Bb1 = (const char*)&lds[s][1][1][0];
    // ph1: kh0, m-half 0 (+ B kh0)
    rd4(a, Ab0 + aoff);
    rd4(b, Bb0 + boff);
    STAGE(0, 0, t + 1, ns);
    PHASE_TAIL();
    mfma16(acc, a, b, 0);
    PHASE_END();
    // ph2: kh0, m-half 1
    rd4(a, Ab0 + aoff + 4096);
    STAGE(1, 0, t + 1, ns);
    PHASE_TAIL();
    mfma16(acc, a, b, 1);
    PHASE_END_V4();  // guarantees kh1(t) landed before ph3 reads (2 newest halves in flight)
    // ph3: kh1, m-half 0 (+ B kh1)
    rd4(a, Ab1 + aoff);
    rd4(b, Bb1 + boff);
    STAGE(0, 1, t + 1, ns);
    PHASE_TAIL();
    mfma16(acc, a, b, 0);
    PHASE_END();
    // ph4: kh1, m-half 1
    rd4(a, Ab1 + aoff + 4096);
    STAGE(1, 1, t + 1, ns);
    PHASE_TAIL();
    mfma16(acc, a, b, 1);
    PHASE_END_V4();  // guarantees kh0(t+1) landed before next ph1 reads
  }

  {  // peeled last K-tile (slot 1), no staging; one vmcnt(0) to cover kh1
    const char* Ab0 = (const char*)&lds[1][0][0][0];
    const char* Bb0 = (const char*)&lds[1][1][0][0];
    const char* Ab1 = (const char*)&lds[1][0][1][0];
    const char* Bb1 = (const char*)&lds[1][1][1][0];
    rd4(a, Ab0 + aoff);
    rd4(b, Bb0 + boff);
    PHASE_TAIL();
    mfma16(acc, a, b, 0);
    PHASE_END();
    rd4(a, Ab0 + aoff + 4096);
    PHASE_TAIL();
    mfma16(acc, a, b, 1);
    __builtin_amdgcn_s_setprio(0);
    VMCNT(0);
    BAR();
    rd4(a, Ab1 + aoff);
    rd4(b, Bb1 + boff);
    PHASE_TAIL();
    mfma16(acc, a, b, 0);
    PHASE_END();
    rd4(a, Ab1 + aoff + 4096);
    PHASE_TAIL();
    mfma16(acc, a, b, 1);
    PHASE_END();
  }

  // epilogue: fp16 rounding + fp16 bias add (reference numerics), fp32 store
  const int kg4 = kg * 4;
#pragma unroll
  for (int nf = 0; nf < 4; ++nf) {
    int col = col0 + wn * 64 + nf * 16 + r16;
    _Float16 bh = (_Float16)bias[col];
#pragma unroll
    for (int mf = 0; mf < 8; ++mf) {
      int rb = row0 + wm * 128 + mf * 16 + kg4;
#pragma unroll
      for (int r = 0; r < 4; ++r) {
        _Float16 v = (_Float16)acc[mf][nf][r] + bh;
        C[(size_t)(rb + r) * OUT_F + col] = (float)v;
      }
    }
  }
}

// ---------------- emergency fallback (ws too small) ----------------
__global__ void naive_k(const float* __restrict__ x, const int* __restrict__ wq,
                        const float* __restrict__ scales, const float* __restrict__ bias,
                        float* __restrict__ out) {
  long idx = (long)blockIdx.x * blockDim.x + threadIdx.x;
  if (idx >= (long)M_TOTAL * OUT_F) return;
  int m = (int)(idx / OUT_F);
  int n = (int)(idx % OUT_F);
  float acc = 0.f;
  for (int g = 0; g < NGROUPS; ++g) {
    float s = scales[n * NGROUPS + g];
    for (int k = g * 128; k < (g + 1) * 128; ++k) {
      _Float16 xv = (_Float16)x[(size_t)m * IN_F + k];
      _Float16 wv = (_Float16)((float)wq[(size_t)n * IN_F + k] * s);
      acc += (float)xv * (float)wv;
    }
  }
  _Float16 r = (_Float16)acc + (_Float16)bias[n];
  out[idx] = (float)r;
}

extern "C" void kernel_launch(void* const* d_in, const int* in_sizes, int n_in,
                              void* d_out, int out_size, void* d_ws, size_t ws_size,
                              hipStream_t stream) {
  const float* x = (const float*)d_in[0];
  const int* wq = (const int*)d_in[1];  // integer inputs arrive as int32
  const float* scales = (const float*)d_in[2];
  const float* bias = (const float*)d_in[3];
  float* out = (float*)d_out;

  const size_t xh_bytes = (size_t)M_TOTAL * IN_F * sizeof(half_t);
  const size_t wh_bytes = (size_t)OUT_F * IN_F * sizeof(half_t);

  if (ws_size >= xh_bytes + wh_bytes) {
    half_t* xh = (half_t*)d_ws;
    half_t* wh = (half_t*)((char*)d_ws + xh_bytes);
    convert_x_k<<<2048, 256, 0, stream>>>(x, xh);
    dequant_w_k<<<OUT_F, 512, 0, stream>>>(wq, scales, wh);
    gemm_k<<<(M_TOTAL / BM) * (OUT_F / BN), 512, 0, stream>>>(xh, wh, bias, out);
  } else {
    long total = (long)M_TOTAL * OUT_F;
    naive_k<<<(int)((total + 255) / 256), 256, 0, stream>>>(x, wq, scales, bias, out);
  }
}

// Round 4
// 826.896 us; speedup vs baseline: 1.4894x; 1.1824x over previous
//
#include <hip/hip_runtime.h>

#define IN_F 4096
#define OUT_F 11008
#define NGROUPS 32
#define M_TOTAL 8192
#define BM 256
#define BN 256
#define BK 64
#define NKT (IN_F / BK)  // 64 K-tiles

typedef _Float16 half_t;
typedef __attribute__((ext_vector_type(8))) _Float16 half8;
typedef __attribute__((ext_vector_type(4))) _Float16 half4v;
typedef __attribute__((ext_vector_type(4))) float f32x4;
typedef __attribute__((ext_vector_type(4))) int i32x4;

typedef __attribute__((address_space(1))) const void gvoid_t;
typedef __attribute__((address_space(3))) void lvoid_t;

// ---------------- prepass 1: x fp32 -> fp16 (RTNE) ----------------
__global__ void convert_x_k(const float* __restrict__ x, half_t* __restrict__ xh) {
  const int n4 = M_TOTAL * IN_F / 4;
  int stride = gridDim.x * blockDim.x;
  for (int i = blockIdx.x * blockDim.x + threadIdx.x; i < n4; i += stride) {
    f32x4 v = __builtin_nontemporal_load((const f32x4*)x + i);  // single-touch
    half4v h;
    h[0] = (_Float16)v[0]; h[1] = (_Float16)v[1];
    h[2] = (_Float16)v[2]; h[3] = (_Float16)v[3];
    ((half4v*)xh)[i] = h;
  }
}

// ---------------- prepass 2: W (int32-materialized int8) * group scale -> fp16 ----------
__global__ void dequant_w_k(const int* __restrict__ wq,
                            const float* __restrict__ scales,
                            half_t* __restrict__ wh) {
  int row = blockIdx.x;
  int t = threadIdx.x;  // 512 threads, 8 weights each
  size_t base = (size_t)row * IN_F + (size_t)t * 8;
  float s = scales[row * NGROUPS + (t >> 4)];
  i32x4 q0 = __builtin_nontemporal_load((const i32x4*)(wq + base));
  i32x4 q1 = __builtin_nontemporal_load((const i32x4*)(wq + base) + 1);
  half8 h;
#pragma unroll
  for (int j = 0; j < 4; ++j) h[j] = (_Float16)((float)q0[j] * s);
#pragma unroll
  for (int j = 0; j < 4; ++j) h[4 + j] = (_Float16)((float)q1[j] * s);
  *(half8*)(wh + base) = h;
}

// ---------------- 256x256 8-phase GEMM: C[M,N] = A[M,K] * B[N,K]^T ----------------
// LDS: [slot][op A=0/B=1][khalf][256 rows x 32 k] fp16 (64 B rows), 128 KiB.
// T2 swizzle byte-col c' = c ^ ((row&6)<<3), pre-swizzled global source + swizzled read.
// Staging units: U0=(A,k0) U1=(B,k0) U2=(A,k1) U3=(B,k1); 2 loads each.
// Reads: U0@p0,p1  U1@p0  U2@p2,p3  U3@p2  (B frags register-reused in mh1 phases).
// Iter t schedule (slot s=t&1): p0 stages U2(t+1)->ns, p1/p2/p3 stage U1/U0/U3(t+2)->s
// into regions freed by the immediately preceding phase; ONE vmcnt(6) per K-tile leaves
// exactly the three t+2 units in flight => tile t+1 fully landed before iter t+1.

__device__ __forceinline__ void rd4(half8 (&d)[4], const char* base) {
#pragma unroll
  for (int i = 0; i < 4; ++i) d[i] = *(const half8*)(base + i * 1024);
}

__device__ __forceinline__ void mfma16(f32x4 (&acc)[8][4], const half8 (&a)[4],
                                       const half8 (&b)[4], int mh) {
#pragma unroll
  for (int i = 0; i < 4; ++i)
#pragma unroll
    for (int j = 0; j < 4; ++j)
      acc[mh * 4 + i][j] =
          __builtin_amdgcn_mfma_f32_16x16x32_f16(a[i], b[j], acc[mh * 4 + i][j], 0, 0, 0);
}

#define BAR() __builtin_amdgcn_s_barrier()
#define VMCNT(N) asm volatile("s_waitcnt vmcnt(" #N ")" ::: "memory")
#define PHASE_TAIL()                                   \
  do {                                                 \
    BAR();                                             \
    asm volatile("s_waitcnt lgkmcnt(0)" ::: "memory"); \
    __builtin_amdgcn_sched_barrier(0);                 \
    __builtin_amdgcn_s_setprio(1);                     \
  } while (0)
#define PHASE_END()                \
  do {                             \
    __builtin_amdgcn_s_setprio(0); \
    BAR();                         \
  } while (0)

#define STAGE(OP, KH, KT, S)                                                          \
  do {                                                                                \
    const half_t* g_ = ((OP) ? pBsrc : pAsrc) + (KT) * 64 + (KH) * 32;                \
    char* d_ = (char*)&lds[S][OP][KH][0] + wvoff;                                     \
    __builtin_amdgcn_global_load_lds((gvoid_t*)g_, (lvoid_t*)d_, 16, 0, 0);           \
    __builtin_amdgcn_global_load_lds((gvoid_t*)(g_ + 128 * IN_F),                     \
                                     (lvoid_t*)(d_ + 8192), 16, 0, 0);                \
  } while (0)

__global__ __launch_bounds__(512, 2) void gemm_k(const half_t* __restrict__ A,
                                                 const half_t* __restrict__ B,
                                                 const float* __restrict__ bias,
                                                 float* __restrict__ C) {
  __shared__ __align__(16) half_t lds[2][2][2][8192];  // 128 KiB

  const int tid = threadIdx.x;
  const int lane = tid & 63;
  const int wv = tid >> 6;
  const int wm = wv >> 2;      // 2 wave-rows (128 rows)
  const int wn = wv & 3;       // 4 wave-cols (64 cols)
  const int wvoff = wv << 10;  // wave-uniform LDS base step

  // XCD-bijective swizzle (nwg = 1376, %8 == 0); bm fastest -> B panel L2-resident
  const int nwg = gridDim.x;
  const int swz = ((int)(blockIdx.x & 7)) * (nwg >> 3) + ((int)blockIdx.x >> 3);
  const int bm = swz & 31;
  const int bn = swz >> 5;
  const int row0 = bm * BM;
  const int col0 = bn * BN;

  // staging source (pre-swizzled; involution c ^= (row&6)<<3)
  const int c16 = (tid & 3) * 16;
  const int srow = tid >> 2;
  const int clog = c16 ^ ((srow & 6) << 3);
  const int kidx = clog >> 1;
  const half_t* pAsrc = A + (size_t)(row0 + srow) * IN_F + kidx;
  const half_t* pBsrc = B + (size_t)(col0 + srow) * IN_F + kidx;

  // fragment read offsets (swizzled); frag stride = 16 rows * 64 B = 1024
  const int r16 = lane & 15;
  const int kg = lane >> 4;
  const int arow = wm * 128 + r16;
  const int brow = wn * 64 + r16;
  const int aoff = arow * 64 + ((kg * 16) ^ ((arow & 6) << 3));
  const int boff = brow * 64 + ((kg * 16) ^ ((brow & 6) << 3));

  f32x4 acc[8][4];
#pragma unroll
  for (int m = 0; m < 8; ++m)
#pragma unroll
    for (int n = 0; n < 4; ++n) acc[m][n] = (f32x4){0.f, 0.f, 0.f, 0.f};

  // prologue: tile0 (4 units) + first 3 units of tile1; vmcnt(6) drains tile0
  STAGE(0, 0, 0, 0);
  STAGE(1, 0, 0, 0);
  STAGE(0, 1, 0, 0);
  STAGE(1, 1, 0, 0);
  STAGE(1, 0, 1, 1);
  STAGE(0, 0, 1, 1);
  STAGE(1, 1, 1, 1);
  VMCNT(6);
  BAR();

  half8 a[4], b[4];
  for (int t = 0; t < NKT - 2; ++t) {
    const int s = t & 1, ns = s ^ 1;
    const char* Ab0 = (const char*)&lds[s][0][0][0];
    const char* Bb0 = (const char*)&lds[s][1][0][0];
    const char* Ab1 = (const char*)&lds[s][0][1][0];
    const char* Bb1 = (const char*)&lds[s][1][1][0];
    // p0: kh0 mh0 ; stage U2(t+1) -> ns A-k1 (freed at iter t-1 p3)
    rd4(a, Ab0 + aoff);
    rd4(b, Bb0 + boff);
    STAGE(0, 1, t + 1, ns);
    PHASE_TAIL();
    mfma16(acc, a, b, 0);
    PHASE_END();
    // p1: kh0 mh1 ; stage U1(t+2) -> s B-k0 (freed by p0-end barrier)
    rd4(a, Ab0 + aoff + 4096);
    STAGE(1, 0, t + 2, s);
    PHASE_TAIL();
    mfma16(acc, a, b, 1);
    PHASE_END();
    // p2: kh1 mh0 ; stage U0(t+2) -> s A-k0 (freed after p1)
    rd4(a, Ab1 + aoff);
    rd4(b, Bb1 + boff);
    STAGE(0, 0, t + 2, s);
    PHASE_TAIL();
    mfma16(acc, a, b, 0);
    PHASE_END();
    // p3: kh1 mh1 ; stage U3(t+2) -> s B-k1 (freed after p2); single fence per K-tile
    rd4(a, Ab1 + aoff + 4096);
    STAGE(1, 1, t + 2, s);
    PHASE_TAIL();
    mfma16(acc, a, b, 1);
    __builtin_amdgcn_s_setprio(0);
    VMCNT(6);  // leaves exactly U1,U0,U3(t+2) in flight; tile t+1 fully landed
    BAR();
  }

  {  // peeled iter NKT-2 (s=0): stage only U2(NKT-1); drain everything at end
    const char* Ab0 = (const char*)&lds[0][0][0][0];
    const char* Bb0 = (const char*)&lds[0][1][0][0];
    const char* Ab1 = (const char*)&lds[0][0][1][0];
    const char* Bb1 = (const char*)&lds[0][1][1][0];
    rd4(a, Ab0 + aoff);
    rd4(b, Bb0 + boff);
    STAGE(0, 1, NKT - 1, 1);
    PHASE_TAIL();
    mfma16(acc, a, b, 0);
    PHASE_END();
    rd4(a, Ab0 + aoff + 4096);
    PHASE_TAIL();
    mfma16(acc, a, b, 1);
    PHASE_END();
    rd4(a, Ab1 + aoff);
    rd4(b, Bb1 + boff);
    PHASE_TAIL();
    mfma16(acc, a, b, 0);
    PHASE_END();
    rd4(a, Ab1 + aoff + 4096);
    PHASE_TAIL();
    mfma16(acc, a, b, 1);
    __builtin_amdgcn_s_setprio(0);
    VMCNT(0);
    BAR();
  }
  {  // peeled iter NKT-1 (s=1): no staging, no fences
    const char* Ab0 = (const char*)&lds[1][0][0][0];
    const char* Bb0 = (const char*)&lds[1][1][0][0];
    const char* Ab1 = (const char*)&lds[1][0][1][0];
    const char* Bb1 = (const char*)&lds[1][1][1][0];
    rd4(a, Ab0 + aoff);
    rd4(b, Bb0 + boff);
    PHASE_TAIL();
    mfma16(acc, a, b, 0);
    PHASE_END();
    rd4(a, Ab0 + aoff + 4096);
    PHASE_TAIL();
    mfma16(acc, a, b, 1);
    PHASE_END();
    rd4(a, Ab1 + aoff);
    rd4(b, Bb1 + boff);
    PHASE_TAIL();
    mfma16(acc, a, b, 0);
    PHASE_END();
    rd4(a, Ab1 + aoff + 4096);
    PHASE_TAIL();
    mfma16(acc, a, b, 1);
    PHASE_END();
  }

  // epilogue: fp16 rounding + fp16 bias add (reference numerics), NT fp32 store
  const int kg4 = kg * 4;
#pragma unroll
  for (int nf = 0; nf < 4; ++nf) {
    int col = col0 + wn * 64 + nf * 16 + r16;
    _Float16 bh = (_Float16)bias[col];
#pragma unroll
    for (int mf = 0; mf < 8; ++mf) {
      int rb = row0 + wm * 128 + mf * 16 + kg4;
#pragma unroll
      for (int r = 0; r < 4; ++r) {
        _Float16 v = (_Float16)acc[mf][nf][r] + bh;
        __builtin_nontemporal_store((float)v, &C[(size_t)(rb + r) * OUT_F + col]);
      }
    }
  }
}

// ---------------- emergency fallback (ws too small) ----------------
__global__ void naive_k(const float* __restrict__ x, const int* __restrict__ wq,
                        const float* __restrict__ scales, const float* __restrict__ bias,
                        float* __restrict__ out) {
  long idx = (long)blockIdx.x * blockDim.x + threadIdx.x;
  if (idx >= (long)M_TOTAL * OUT_F) return;
  int m = (int)(idx / OUT_F);
  int n = (int)(idx % OUT_F);
  float acc = 0.f;
  for (int g = 0; g < NGROUPS; ++g) {
    float s = scales[n * NGROUPS + g];
    for (int k = g * 128; k < (g + 1) * 128; ++k) {
      _Float16 xv = (_Float16)x[(size_t)m * IN_F + k];
      _Float16 wv = (_Float16)((float)wq[(size_t)n * IN_F + k] * s);
      acc += (float)xv * (float)wv;
    }
  }
  _Float16 r = (_Float16)acc + (_Float16)bias[n];
  out[idx] = (float)r;
}

extern "C" void kernel_launch(void* const* d_in, const int* in_sizes, int n_in,
                              void* d_out, int out_size, void* d_ws, size_t ws_size,
                              hipStream_t stream) {
  const float* x = (const float*)d_in[0];
  const int* wq = (const int*)d_in[1];  // integer inputs arrive as int32
  const float* scales = (const float*)d_in[2];
  const float* bias = (const float*)d_in[3];
  float* out = (float*)d_out;

  const size_t xh_bytes = (size_t)M_TOTAL * IN_F * sizeof(half_t);
  const size_t wh_bytes = (size_t)OUT_F * IN_F * sizeof(half_t);

  if (ws_size >= xh_bytes + wh_bytes) {
    half_t* xh = (half_t*)d_ws;
    half_t* wh = (half_t*)((char*)d_ws + xh_bytes);
    convert_x_k<<<2048, 256, 0, stream>>>(x, xh);
    dequant_w_k<<<OUT_F, 512, 0, stream>>>(wq, scales, wh);
    gemm_k<<<(M_TOTAL / BM) * (OUT_F / BN), 512, 0, stream>>>(xh, wh, bias, out);
  } else {
    long total = (long)M_TOTAL * OUT_F;
    naive_k<<<(int)((total + 255) / 256), 256, 0, stream>>>(x, wq, scales, bias, out);
  }
}

// Round 5
// 799.970 us; speedup vs baseline: 1.5395x; 1.0337x over previous
//
#include <hip/hip_runtime.h>

#define IN_F 4096
#define OUT_F 11008
#define NGROUPS 32
#define M_TOTAL 8192
#define BM 256
#define BN 256
#define BK 64
#define NKT (IN_F / BK)  // 64 K-tiles, 256 phases

typedef _Float16 half_t;
typedef __attribute__((ext_vector_type(8))) _Float16 half8;
typedef __attribute__((ext_vector_type(4))) _Float16 half4v;
typedef __attribute__((ext_vector_type(4))) float f32x4;
typedef __attribute__((ext_vector_type(4))) int i32x4;

typedef __attribute__((address_space(1))) const void gvoid_t;
typedef __attribute__((address_space(3))) void lvoid_t;

// ---------------- prepass 1: x fp32 -> fp16 (RTNE) ----------------
__global__ void convert_x_k(const float* __restrict__ x, half_t* __restrict__ xh) {
  const int n4 = M_TOTAL * IN_F / 4;
  int stride = gridDim.x * blockDim.x;
  for (int i = blockIdx.x * blockDim.x + threadIdx.x; i < n4; i += stride) {
    f32x4 v = __builtin_nontemporal_load((const f32x4*)x + i);
    half4v h;
    h[0] = (_Float16)v[0]; h[1] = (_Float16)v[1];
    h[2] = (_Float16)v[2]; h[3] = (_Float16)v[3];
    ((half4v*)xh)[i] = h;
  }
}

// ---------------- prepass 2: W (int32-materialized int8) * group scale -> fp16 ----------
__global__ void dequant_w_k(const int* __restrict__ wq,
                            const float* __restrict__ scales,
                            half_t* __restrict__ wh) {
  int row = blockIdx.x;
  int t = threadIdx.x;  // 512 threads, 8 weights each
  size_t base = (size_t)row * IN_F + (size_t)t * 8;
  float s = scales[row * NGROUPS + (t >> 4)];
  i32x4 q0 = __builtin_nontemporal_load((const i32x4*)(wq + base));
  i32x4 q1 = __builtin_nontemporal_load((const i32x4*)(wq + base) + 1);
  half8 h;
#pragma unroll
  for (int j = 0; j < 4; ++j) h[j] = (_Float16)((float)q0[j] * s);
#pragma unroll
  for (int j = 0; j < 4; ++j) h[4 + j] = (_Float16)((float)q1[j] * s);
  *(half8*)(wh + base) = h;
}

// ---------------- 256x256 GEMM with 1-phase ds_read-ahead pipeline ----------------
// LDS: [slot][op][khalf][256x32] fp16, 128 KiB. T2 swizzle c ^= (row&6)<<3 both sides.
// Stage ledger (unit n = 4*tile+k staged at phase n-6, 2 loads/unit):
//   phase 4t+0: A-kh1(t+1)  4t+1: B-kh1(t+1)  4t+2: A-kh0(t+2)  4t+3: B-kh0(t+2)
// vmcnt(6) per phase => completed units <= g+3; reads-ahead at g touch units <= g+2;
// in-flight writes {g+4..g+6} — disjoint. Every stage's target region was lgkm-drained
// >=1 barrier before the stage issues (4 cases verified).
// Per phase: [reads for g+1][stage][lgkmcnt(R) counted][MFMA on g's regs][vmcnt(6)][bar]

__device__ __forceinline__ void rd4(half8 (&d)[4], const char* base) {
#pragma unroll
  for (int i = 0; i < 4; ++i) d[i] = *(const half8*)(base + i * 1024);
}

__device__ __forceinline__ void mfma16(f32x4 (&acc)[8][4], const half8 (&a)[4],
                                       const half8 (&b)[4], int mh) {
#pragma unroll
  for (int i = 0; i < 4; ++i)
#pragma unroll
    for (int j = 0; j < 4; ++j)
      acc[mh * 4 + i][j] =
          __builtin_amdgcn_mfma_f32_16x16x32_f16(a[i], b[j], acc[mh * 4 + i][j], 0, 0, 0);
}

#define BAR() __builtin_amdgcn_s_barrier()
#define SB0() __builtin_amdgcn_sched_barrier(0)
#define PRIO1() __builtin_amdgcn_s_setprio(1)
#define PRIO0() __builtin_amdgcn_s_setprio(0)
#define VMCNT(N) asm volatile("s_waitcnt vmcnt(" #N ")" ::: "memory")
#define LGKM(N) asm volatile("s_waitcnt lgkmcnt(" #N ")" ::: "memory")

#define STAGE(OP, KH, KT, S)                                                          \
  do {                                                                                \
    const half_t* g_ = ((OP) ? pBsrc : pAsrc) + (KT) * 64 + (KH) * 32;                \
    char* d_ = (char*)&lds[S][OP][KH][0] + wvoff;                                     \
    __builtin_amdgcn_global_load_lds((gvoid_t*)g_, (lvoid_t*)d_, 16, 0, 0);           \
    __builtin_amdgcn_global_load_lds((gvoid_t*)(g_ + 128 * IN_F),                     \
                                     (lvoid_t*)(d_ + 8192), 16, 0, 0);                \
  } while (0)

__global__ __launch_bounds__(512, 2) void gemm_k(const half_t* __restrict__ A,
                                                 const half_t* __restrict__ B,
                                                 const float* __restrict__ bias,
                                                 float* __restrict__ C) {
  __shared__ __align__(16) half_t lds[2][2][2][8192];  // 128 KiB

  const int tid = threadIdx.x;
  const int lane = tid & 63;
  const int wv = tid >> 6;
  const int wm = wv >> 2;
  const int wn = wv & 3;
  const int wvoff = wv << 10;

  const int nwg = gridDim.x;
  const int swz = ((int)(blockIdx.x & 7)) * (nwg >> 3) + ((int)blockIdx.x >> 3);
  const int bm = swz & 31;
  const int bn = swz >> 5;
  const int row0 = bm * BM;
  const int col0 = bn * BN;

  const int c16 = (tid & 3) * 16;
  const int srow = tid >> 2;
  const int clog = c16 ^ ((srow & 6) << 3);
  const int kidx = clog >> 1;
  const half_t* pAsrc = A + (size_t)(row0 + srow) * IN_F + kidx;
  const half_t* pBsrc = B + (size_t)(col0 + srow) * IN_F + kidx;

  const int r16 = lane & 15;
  const int kg = lane >> 4;
  const int arow = wm * 128 + r16;
  const int brow = wn * 64 + r16;
  const int aoff = arow * 64 + ((kg * 16) ^ ((arow & 6) << 3));
  const int boff = brow * 64 + ((kg * 16) ^ ((brow & 6) << 3));

  f32x4 acc[8][4];
#pragma unroll
  for (int m = 0; m < 8; ++m)
#pragma unroll
    for (int n = 0; n < 4; ++n) acc[m][n] = (f32x4){0.f, 0.f, 0.f, 0.f};

  // prologue: units 0..5 (tile0 all + tile1 kh0 A,B); vmcnt(8) => units 0,1 landed
  STAGE(0, 0, 0, 0);
  STAGE(1, 0, 0, 0);
  STAGE(0, 1, 0, 0);
  STAGE(1, 1, 0, 0);
  STAGE(0, 0, 1, 1);
  STAGE(1, 0, 1, 1);
  VMCNT(8);
  BAR();
  SB0();

  half8 aR0[4], aR1[4], bR0[4], bR1[4];
  rd4(aR0, (const char*)&lds[0][0][0][0] + aoff);  // A-kh0-mh0(0)
  rd4(bR0, (const char*)&lds[0][1][0][0] + boff);  // B-kh0(0)

  for (int t = 0; t < NKT - 2; ++t) {  // t = 0..61
    const int s = t & 1, ns = s ^ 1;
    const char* Ab0 = (const char*)&lds[s][0][0][0];
    const char* Bb0 = (const char*)&lds[s][1][0][0];
    const char* Ab1 = (const char*)&lds[s][0][1][0];
    const char* Bb1 = (const char*)&lds[s][1][1][0];
    const char* Ab0n = (const char*)&lds[ns][0][0][0];
    const char* Bb0n = (const char*)&lds[ns][1][0][0];
    // p0: ahead A-kh0-mh1(t); MFMA kh0-mh0
    rd4(aR1, Ab0 + aoff + 4096);
    STAGE(0, 1, t + 1, ns);
    LGKM(4); SB0(); PRIO1();
    mfma16(acc, aR0, bR0, 0);
    PRIO0(); VMCNT(6); BAR(); SB0();
    // p1: ahead A-kh1-mh0(t) + B-kh1(t); MFMA kh0-mh1
    rd4(aR0, Ab1 + aoff);
    rd4(bR1, Bb1 + boff);
    STAGE(1, 1, t + 1, ns);
    LGKM(8); SB0(); PRIO1();
    mfma16(acc, aR1, bR0, 1);
    PRIO0(); VMCNT(6); BAR(); SB0();
    // p2: ahead A-kh1-mh1(t); MFMA kh1-mh0
    rd4(aR1, Ab1 + aoff + 4096);
    STAGE(0, 0, t + 2, s);
    LGKM(4); SB0(); PRIO1();
    mfma16(acc, aR0, bR1, 0);
    PRIO0(); VMCNT(6); BAR(); SB0();
    // p3: ahead A-kh0-mh0(t+1) + B-kh0(t+1) from next slot; MFMA kh1-mh1
    rd4(aR0, Ab0n + aoff);
    rd4(bR0, Bb0n + boff);
    STAGE(1, 0, t + 2, s);
    LGKM(8); SB0(); PRIO1();
    mfma16(acc, aR1, bR1, 1);
    PRIO0(); VMCNT(6); BAR(); SB0();
  }

  {  // iter 62 (s=0, ns=1): p0/p1 stage last units (A/B-kh1 of 63); p2/p3 drain 4,0
    const char* Ab0 = (const char*)&lds[0][0][0][0];
    const char* Bb0 = (const char*)&lds[0][1][0][0];
    const char* Ab1 = (const char*)&lds[0][0][1][0];
    const char* Bb1 = (const char*)&lds[0][1][1][0];
    const char* Ab0n = (const char*)&lds[1][0][0][0];
    const char* Bb0n = (const char*)&lds[1][1][0][0];
    rd4(aR1, Ab0 + aoff + 4096);
    STAGE(0, 1, 63, 1);
    LGKM(4); SB0(); PRIO1();
    mfma16(acc, aR0, bR0, 0);
    PRIO0(); VMCNT(6); BAR(); SB0();
    rd4(aR0, Ab1 + aoff);
    rd4(bR1, Bb1 + boff);
    STAGE(1, 1, 63, 1);
    LGKM(8); SB0(); PRIO1();
    mfma16(acc, aR1, bR0, 1);
    PRIO0(); VMCNT(6); BAR(); SB0();
    rd4(aR1, Ab1 + aoff + 4096);
    LGKM(4); SB0(); PRIO1();
    mfma16(acc, aR0, bR1, 0);
    PRIO0(); VMCNT(4); BAR(); SB0();
    rd4(aR0, Ab0n + aoff);
    rd4(bR0, Bb0n + boff);
    LGKM(8); SB0(); PRIO1();
    mfma16(acc, aR1, bR1, 1);
    PRIO0(); VMCNT(0); BAR(); SB0();
  }
  {  // iter 63 (s=1): all data resident; no stages, no fences/barriers needed
    const char* Ab0 = (const char*)&lds[1][0][0][0];
    const char* Ab1 = (const char*)&lds[1][0][1][0];
    const char* Bb1 = (const char*)&lds[1][1][1][0];
    rd4(aR1, Ab0 + aoff + 4096);
    LGKM(4); SB0();
    mfma16(acc, aR0, bR0, 0);
    rd4(aR0, Ab1 + aoff);
    rd4(bR1, Bb1 + boff);
    LGKM(8); SB0();
    mfma16(acc, aR1, bR0, 1);
    rd4(aR1, Ab1 + aoff + 4096);
    LGKM(4); SB0();
    mfma16(acc, aR0, bR1, 0);
    LGKM(0); SB0();
    mfma16(acc, aR1, bR1, 1);
  }

  // epilogue: fp16 rounding + fp16 bias add (reference numerics), NT fp32 store
  const int kg4 = kg * 4;
#pragma unroll
  for (int nf = 0; nf < 4; ++nf) {
    int col = col0 + wn * 64 + nf * 16 + r16;
    _Float16 bh = (_Float16)bias[col];
#pragma unroll
    for (int mf = 0; mf < 8; ++mf) {
      int rb = row0 + wm * 128 + mf * 16 + kg4;
#pragma unroll
      for (int r = 0; r < 4; ++r) {
        _Float16 v = (_Float16)acc[mf][nf][r] + bh;
        __builtin_nontemporal_store((float)v, &C[(size_t)(rb + r) * OUT_F + col]);
      }
    }
  }
}

// ---------------- emergency fallback (ws too small) ----------------
__global__ void naive_k(const float* __restrict__ x, const int* __restrict__ wq,
                        const float* __restrict__ scales, const float* __restrict__ bias,
                        float* __restrict__ out) {
  long idx = (long)blockIdx.x * blockDim.x + threadIdx.x;
  if (idx >= (long)M_TOTAL * OUT_F) return;
  int m = (int)(idx / OUT_F);
  int n = (int)(idx % OUT_F);
  float acc = 0.f;
  for (int g = 0; g < NGROUPS; ++g) {
    float s = scales[n * NGROUPS + g];
    for (int k = g * 128; k < (g + 1) * 128; ++k) {
      _Float16 xv = (_Float16)x[(size_t)m * IN_F + k];
      _Float16 wv = (_Float16)((float)wq[(size_t)n * IN_F + k] * s);
      acc += (float)xv * (float)wv;
    }
  }
  _Float16 r = (_Float16)acc + (_Float16)bias[n];
  out[idx] = (float)r;
}

extern "C" void kernel_launch(void* const* d_in, const int* in_sizes, int n_in,
                              void* d_out, int out_size, void* d_ws, size_t ws_size,
                              hipStream_t stream) {
  const float* x = (const float*)d_in[0];
  const int* wq = (const int*)d_in[1];
  const float* scales = (const float*)d_in[2];
  const float* bias = (const float*)d_in[3];
  float* out = (float*)d_out;

  const size_t xh_bytes = (size_t)M_TOTAL * IN_F * sizeof(half_t);
  const size_t wh_bytes = (size_t)OUT_F * IN_F * sizeof(half_t);

  if (ws_size >= xh_bytes + wh_bytes) {
    half_t* xh = (half_t*)d_ws;
    half_t* wh = (half_t*)((char*)d_ws + xh_bytes);
    convert_x_k<<<2048, 256, 0, stream>>>(x, xh);
    dequant_w_k<<<OUT_F, 512, 0, stream>>>(wq, scales, wh);
    gemm_k<<<(M_TOTAL / BM) * (OUT_F / BN), 512, 0, stream>>>(xh, wh, bias, out);
  } else {
    long total = (long)M_TOTAL * OUT_F;
    naive_k<<<(int)((total + 255) / 256), 256, 0, stream>>>(x, wq, scales, bias, out);
  }
}

// Round 6
// 754.455 us; speedup vs baseline: 1.6324x; 1.0603x over previous
//
#include <hip/hip_runtime.h>

#define IN_F 4096
#define OUT_F 11008
#define NGROUPS 32
#define M_TOTAL 8192
#define BM 256
#define BN 256
#define BK 64
#define NKT (IN_F / BK)  // 64 K-tiles, 256 phases

typedef _Float16 half_t;
typedef __attribute__((ext_vector_type(8))) _Float16 half8;
typedef __attribute__((ext_vector_type(4))) _Float16 half4v;
typedef __attribute__((ext_vector_type(4))) float f32x4;
typedef __attribute__((ext_vector_type(4))) int i32x4;

typedef __attribute__((address_space(1))) const void gvoid_t;
typedef __attribute__((address_space(3))) void lvoid_t;

// ---------------- prepass 1: x fp32 -> fp16 (RTNE) ----------------
__global__ void convert_x_k(const float* __restrict__ x, half_t* __restrict__ xh) {
  const int n4 = M_TOTAL * IN_F / 4;
  int stride = gridDim.x * blockDim.x;
  for (int i = blockIdx.x * blockDim.x + threadIdx.x; i < n4; i += stride) {
    f32x4 v = __builtin_nontemporal_load((const f32x4*)x + i);
    half4v h;
    h[0] = (_Float16)v[0]; h[1] = (_Float16)v[1];
    h[2] = (_Float16)v[2]; h[3] = (_Float16)v[3];
    ((half4v*)xh)[i] = h;
  }
}

// ---------------- prepass 2: W (int32-materialized int8) * group scale -> fp16 ----------
__global__ void dequant_w_k(const int* __restrict__ wq,
                            const float* __restrict__ scales,
                            half_t* __restrict__ wh) {
  int row = blockIdx.x;
  int t = threadIdx.x;  // 512 threads, 8 weights each
  size_t base = (size_t)row * IN_F + (size_t)t * 8;
  float s = scales[row * NGROUPS + (t >> 4)];
  i32x4 q0 = __builtin_nontemporal_load((const i32x4*)(wq + base));
  i32x4 q1 = __builtin_nontemporal_load((const i32x4*)(wq + base) + 1);
  half8 h;
#pragma unroll
  for (int j = 0; j < 4; ++j) h[j] = (_Float16)((float)q0[j] * s);
#pragma unroll
  for (int j = 0; j < 4; ++j) h[4 + j] = (_Float16)((float)q1[j] * s);
  *(half8*)(wh + base) = h;
}

// ---------------- 256x256 GEMM, 1-phase ds_read-ahead pipeline (r5) ----------------
// ROUND 6 CHANGE: band-rasterized block map. Per-XCD linear L traverses bands of
// 32 bm x 4 bn (bn fastest). Co-resident 32-block window per XCD spans <=9 bm x 4 bn
// -> A-stripes shared x4, B-stripes x8 in that XCD's L2; L3/HBM staging traffic ~2.8x down.
// Everything else identical to r5 (ledger re-verified unchanged).

__device__ __forceinline__ void rd4(half8 (&d)[4], const char* base) {
#pragma unroll
  for (int i = 0; i < 4; ++i) d[i] = *(const half8*)(base + i * 1024);
}

__device__ __forceinline__ void mfma16(f32x4 (&acc)[8][4], const half8 (&a)[4],
                                       const half8 (&b)[4], int mh) {
#pragma unroll
  for (int i = 0; i < 4; ++i)
#pragma unroll
    for (int j = 0; j < 4; ++j)
      acc[mh * 4 + i][j] =
          __builtin_amdgcn_mfma_f32_16x16x32_f16(a[i], b[j], acc[mh * 4 + i][j], 0, 0, 0);
}

#define BAR() __builtin_amdgcn_s_barrier()
#define SB0() __builtin_amdgcn_sched_barrier(0)
#define PRIO1() __builtin_amdgcn_s_setprio(1)
#define PRIO0() __builtin_amdgcn_s_setprio(0)
#define VMCNT(N) asm volatile("s_waitcnt vmcnt(" #N ")" ::: "memory")
#define LGKM(N) asm volatile("s_waitcnt lgkmcnt(" #N ")" ::: "memory")

#define STAGE(OP, KH, KT, S)                                                          \
  do {                                                                                \
    const half_t* g_ = ((OP) ? pBsrc : pAsrc) + (KT) * 64 + (KH) * 32;                \
    char* d_ = (char*)&lds[S][OP][KH][0] + wvoff;                                     \
    __builtin_amdgcn_global_load_lds((gvoid_t*)g_, (lvoid_t*)d_, 16, 0, 0);           \
    __builtin_amdgcn_global_load_lds((gvoid_t*)(g_ + 128 * IN_F),                     \
                                     (lvoid_t*)(d_ + 8192), 16, 0, 0);                \
  } while (0)

__global__ __launch_bounds__(512, 2) void gemm_k(const half_t* __restrict__ A,
                                                 const half_t* __restrict__ B,
                                                 const float* __restrict__ bias,
                                                 float* __restrict__ C) {
  __shared__ __align__(16) half_t lds[2][2][2][8192];  // 128 KiB

  const int tid = threadIdx.x;
  const int lane = tid & 63;
  const int wv = tid >> 6;
  const int wm = wv >> 2;
  const int wn = wv & 3;
  const int wvoff = wv << 10;

  // Band-rasterized, XCD-aware mapping (nwg = 1376 = 8 * 172, bijective):
  // L = xcd*172 + seq ; band of 128 L's = 32 bm x 4 bn, bn fastest.
  const int nwg = gridDim.x;
  const int perx = nwg >> 3;  // 172
  const int L = ((int)blockIdx.x & 7) * perx + ((int)blockIdx.x >> 3);
  const int band = L >> 7;
  const int rr_ = L & 127;
  const int bn0 = band << 2;
  const int cols = (43 - bn0) < 4 ? (43 - bn0) : 4;  // last band has 3 columns
  const int bm = rr_ / cols;
  const int bn = bn0 + rr_ % cols;
  const int row0 = bm * BM;
  const int col0 = bn * BN;

  const int c16 = (tid & 3) * 16;
  const int srow = tid >> 2;
  const int clog = c16 ^ ((srow & 6) << 3);
  const int kidx = clog >> 1;
  const half_t* pAsrc = A + (size_t)(row0 + srow) * IN_F + kidx;
  const half_t* pBsrc = B + (size_t)(col0 + srow) * IN_F + kidx;

  const int r16 = lane & 15;
  const int kg = lane >> 4;
  const int arow = wm * 128 + r16;
  const int brow = wn * 64 + r16;
  const int aoff = arow * 64 + ((kg * 16) ^ ((arow & 6) << 3));
  const int boff = brow * 64 + ((kg * 16) ^ ((brow & 6) << 3));

  f32x4 acc[8][4];
#pragma unroll
  for (int m = 0; m < 8; ++m)
#pragma unroll
    for (int n = 0; n < 4; ++n) acc[m][n] = (f32x4){0.f, 0.f, 0.f, 0.f};

  // prologue: units 0..5 (tile0 all + tile1 kh0 A,B); vmcnt(8) => units 0,1 landed
  STAGE(0, 0, 0, 0);
  STAGE(1, 0, 0, 0);
  STAGE(0, 1, 0, 0);
  STAGE(1, 1, 0, 0);
  STAGE(0, 0, 1, 1);
  STAGE(1, 0, 1, 1);
  VMCNT(8);
  BAR();
  SB0();

  half8 aR0[4], aR1[4], bR0[4], bR1[4];
  rd4(aR0, (const char*)&lds[0][0][0][0] + aoff);  // A-kh0-mh0(0)
  rd4(bR0, (const char*)&lds[0][1][0][0] + boff);  // B-kh0(0)

  for (int t = 0; t < NKT - 2; ++t) {  // t = 0..61
    const int s = t & 1, ns = s ^ 1;
    const char* Ab0 = (const char*)&lds[s][0][0][0];
    const char* Bb0 = (const char*)&lds[s][1][0][0];
    const char* Ab1 = (const char*)&lds[s][0][1][0];
    const char* Bb1 = (const char*)&lds[s][1][1][0];
    const char* Ab0n = (const char*)&lds[ns][0][0][0];
    const char* Bb0n = (const char*)&lds[ns][1][0][0];
    // p0: ahead A-kh0-mh1(t); MFMA kh0-mh0
    rd4(aR1, Ab0 + aoff + 4096);
    STAGE(0, 1, t + 1, ns);
    LGKM(4); SB0(); PRIO1();
    mfma16(acc, aR0, bR0, 0);
    PRIO0(); VMCNT(6); BAR(); SB0();
    // p1: ahead A-kh1-mh0(t) + B-kh1(t); MFMA kh0-mh1
    rd4(aR0, Ab1 + aoff);
    rd4(bR1, Bb1 + boff);
    STAGE(1, 1, t + 1, ns);
    LGKM(8); SB0(); PRIO1();
    mfma16(acc, aR1, bR0, 1);
    PRIO0(); VMCNT(6); BAR(); SB0();
    // p2: ahead A-kh1-mh1(t); MFMA kh1-mh0
    rd4(aR1, Ab1 + aoff + 4096);
    STAGE(0, 0, t + 2, s);
    LGKM(4); SB0(); PRIO1();
    mfma16(acc, aR0, bR1, 0);
    PRIO0(); VMCNT(6); BAR(); SB0();
    // p3: ahead A-kh0-mh0(t+1) + B-kh0(t+1) from next slot; MFMA kh1-mh1
    rd4(aR0, Ab0n + aoff);
    rd4(bR0, Bb0n + boff);
    STAGE(1, 0, t + 2, s);
    LGKM(8); SB0(); PRIO1();
    mfma16(acc, aR1, bR1, 1);
    PRIO0(); VMCNT(6); BAR(); SB0();
  }

  {  // iter 62 (s=0, ns=1): p0/p1 stage last units (A/B-kh1 of 63); p2/p3 drain 4,0
    const char* Ab0 = (const char*)&lds[0][0][0][0];
    const char* Bb0 = (const char*)&lds[0][1][0][0];
    const char* Ab1 = (const char*)&lds[0][0][1][0];
    const char* Bb1 = (const char*)&lds[0][1][1][0];
    const char* Ab0n = (const char*)&lds[1][0][0][0];
    const char* Bb0n = (const char*)&lds[1][1][0][0];
    rd4(aR1, Ab0 + aoff + 4096);
    STAGE(0, 1, 63, 1);
    LGKM(4); SB0(); PRIO1();
    mfma16(acc, aR0, bR0, 0);
    PRIO0(); VMCNT(6); BAR(); SB0();
    rd4(aR0, Ab1 + aoff);
    rd4(bR1, Bb1 + boff);
    STAGE(1, 1, 63, 1);
    LGKM(8); SB0(); PRIO1();
    mfma16(acc, aR1, bR0, 1);
    PRIO0(); VMCNT(6); BAR(); SB0();
    rd4(aR1, Ab1 + aoff + 4096);
    LGKM(4); SB0(); PRIO1();
    mfma16(acc, aR0, bR1, 0);
    PRIO0(); VMCNT(4); BAR(); SB0();
    rd4(aR0, Ab0n + aoff);
    rd4(bR0, Bb0n + boff);
    LGKM(8); SB0(); PRIO1();
    mfma16(acc, aR1, bR1, 1);
    PRIO0(); VMCNT(0); BAR(); SB0();
  }
  {  // iter 63 (s=1): all data resident; no stages, no fences/barriers needed
    const char* Ab0 = (const char*)&lds[1][0][0][0];
    const char* Ab1 = (const char*)&lds[1][0][1][0];
    const char* Bb1 = (const char*)&lds[1][1][1][0];
    rd4(aR1, Ab0 + aoff + 4096);
    LGKM(4); SB0();
    mfma16(acc, aR0, bR0, 0);
    rd4(aR0, Ab1 + aoff);
    rd4(bR1, Bb1 + boff);
    LGKM(8); SB0();
    mfma16(acc, aR1, bR0, 1);
    rd4(aR1, Ab1 + aoff + 4096);
    LGKM(4); SB0();
    mfma16(acc, aR0, bR1, 0);
    LGKM(0); SB0();
    mfma16(acc, aR1, bR1, 1);
  }

  // epilogue: fp16 rounding + fp16 bias add (reference numerics), NT fp32 store
  const int kg4 = kg * 4;
#pragma unroll
  for (int nf = 0; nf < 4; ++nf) {
    int col = col0 + wn * 64 + nf * 16 + r16;
    _Float16 bh = (_Float16)bias[col];
#pragma unroll
    for (int mf = 0; mf < 8; ++mf) {
      int rb = row0 + wm * 128 + mf * 16 + kg4;
#pragma unroll
      for (int r = 0; r < 4; ++r) {
        _Float16 v = (_Float16)acc[mf][nf][r] + bh;
        __builtin_nontemporal_store((float)v, &C[(size_t)(rb + r) * OUT_F + col]);
      }
    }
  }
}

// ---------------- emergency fallback (ws too small) ----------------
__global__ void naive_k(const float* __restrict__ x, const int* __restrict__ wq,
                        const float* __restrict__ scales, const float* __restrict__ bias,
                        float* __restrict__ out) {
  long idx = (long)blockIdx.x * blockDim.x + threadIdx.x;
  if (idx >= (long)M_TOTAL * OUT_F) return;
  int m = (int)(idx / OUT_F);
  int n = (int)(idx % OUT_F);
  float acc = 0.f;
  for (int g = 0; g < NGROUPS; ++g) {
    float s = scales[n * NGROUPS + g];
    for (int k = g * 128; k < (g + 1) * 128; ++k) {
      _Float16 xv = (_Float16)x[(size_t)m * IN_F + k];
      _Float16 wv = (_Float16)((float)wq[(size_t)n * IN_F + k] * s);
      acc += (float)xv * (float)wv;
    }
  }
  _Float16 r = (_Float16)acc + (_Float16)bias[n];
  out[idx] = (float)r;
}

extern "C" void kernel_launch(void* const* d_in, const int* in_sizes, int n_in,
                              void* d_out, int out_size, void* d_ws, size_t ws_size,
                              hipStream_t stream) {
  const float* x = (const float*)d_in[0];
  const int* wq = (const int*)d_in[1];
  const float* scales = (const float*)d_in[2];
  const float* bias = (const float*)d_in[3];
  float* out = (float*)d_out;

  const size_t xh_bytes = (size_t)M_TOTAL * IN_F * sizeof(half_t);
  const size_t wh_bytes = (size_t)OUT_F * IN_F * sizeof(half_t);

  if (ws_size >= xh_bytes + wh_bytes) {
    half_t* xh = (half_t*)d_ws;
    half_t* wh = (half_t*)((char*)d_ws + xh_bytes);
    convert_x_k<<<2048, 256, 0, stream>>>(x, xh);
    dequant_w_k<<<OUT_F, 512, 0, stream>>>(wq, scales, wh);
    gemm_k<<<(M_TOTAL / BM) * (OUT_F / BN), 512, 0, stream>>>(xh, wh, bias, out);
  } else {
    long total = (long)M_TOTAL * OUT_F;
    naive_k<<<(int)((total + 255) / 256), 256, 0, stream>>>(x, wq, scales, bias, out);
  }
}